// Round 1
// baseline (392.514 us; speedup 1.0000x reference)
//
#include <hip/hip_runtime.h>
#include <math.h>

#define B_N 2
#define S_N 8
#define H_N 32
#define W_N 32
#define DIM_N 256
#define NPOS (B_N * S_N * H_N * W_N)   // 16384
#define HEADS_N 8
#define DH_N 32
#define SCALE_F 0.1767766952966369f    // 32^-0.5

#define BM 128
#define BN 128
#define BK 32
#define LDST 132   // padded LDS row stride (floats)

// ---------------- generic fp32 tiled GEMM body ----------------
// out[row0:row0+128, col0:col0+128] = A[rows,256] @ W[256,256] (+bias)
__device__ __forceinline__ void gemm_tile_body(
    const float* __restrict__ A, const float* __restrict__ Wm,
    const float* __restrict__ bias, float* __restrict__ out,
    int row0, int col0)
{
    __shared__ float Ast[BK][LDST];   // transposed: [kk][row]
    __shared__ float Bs[BK][LDST];    // [kk][col]

    const int tid = threadIdx.x;
    const int tx = tid & 15;   // col group
    const int ty = tid >> 4;   // row group

    float acc[8][8];
#pragma unroll
    for (int i = 0; i < 8; ++i)
#pragma unroll
        for (int j = 0; j < 8; ++j) acc[i][j] = 0.f;

    for (int k0 = 0; k0 < DIM_N; k0 += BK) {
        // A tile: 128 rows x 32 k, store transposed
#pragma unroll
        for (int i = 0; i < 16; ++i) {
            int e = tid + i * 256;
            int r = e >> 5;      // 0..127
            int c = e & 31;      // 0..31
            Ast[c][r] = A[(size_t)(row0 + r) * DIM_N + k0 + c];
        }
        // B tile: 32 k x 128 cols
#pragma unroll
        for (int i = 0; i < 16; ++i) {
            int e = tid + i * 256;
            int r = e >> 7;      // 0..31
            int c = e & 127;     // 0..127
            Bs[r][c] = Wm[(size_t)(k0 + r) * DIM_N + col0 + c];
        }
        __syncthreads();
#pragma unroll
        for (int kk = 0; kk < BK; ++kk) {
            float4 a0 = *(const float4*)&Ast[kk][ty * 4];
            float4 a1 = *(const float4*)&Ast[kk][64 + ty * 4];
            float4 b0 = *(const float4*)&Bs[kk][tx * 4];
            float4 b1 = *(const float4*)&Bs[kk][64 + tx * 4];
            float a[8] = {a0.x, a0.y, a0.z, a0.w, a1.x, a1.y, a1.z, a1.w};
            float b[8] = {b0.x, b0.y, b0.z, b0.w, b1.x, b1.y, b1.z, b1.w};
#pragma unroll
            for (int i = 0; i < 8; ++i)
#pragma unroll
                for (int j = 0; j < 8; ++j)
                    acc[i][j] = fmaf(a[i], b[j], acc[i][j]);
        }
        __syncthreads();
    }
    // epilogue: rows {ty*4+0..3, 64+ty*4+0..3}, cols {tx*4+0..3, 64+tx*4+0..3}
#pragma unroll
    for (int i = 0; i < 8; ++i) {
        int r = row0 + ((i < 4) ? (ty * 4 + i) : (64 + ty * 4 + (i - 4)));
#pragma unroll
        for (int jh = 0; jh < 2; ++jh) {
            int cbase = col0 + jh * 64 + tx * 4;
            float4 v;
            v.x = acc[i][jh * 4 + 0];
            v.y = acc[i][jh * 4 + 1];
            v.z = acc[i][jh * 4 + 2];
            v.w = acc[i][jh * 4 + 3];
            if (bias) {
                v.x += bias[cbase + 0];
                v.y += bias[cbase + 1];
                v.z += bias[cbase + 2];
                v.w += bias[cbase + 3];
            }
            *(float4*)&out[(size_t)r * DIM_N + cbase] = v;
        }
    }
}

__global__ __launch_bounds__(256, 4)
void proj_kernel(const float* __restrict__ x, const float* __restrict__ q,
                 const float* __restrict__ Wq, const float* __restrict__ Wk,
                 const float* __restrict__ Wv, const float* __restrict__ bv,
                 float* __restrict__ qp, float* __restrict__ kb,
                 float* __restrict__ vb)
{
    int mat = blockIdx.z;
    const float* A = (mat == 0) ? q : x;
    const float* Wm = (mat == 0) ? Wq : ((mat == 1) ? Wk : Wv);
    const float* bias = (mat == 2) ? bv : nullptr;
    float* out = (mat == 0) ? qp : ((mat == 1) ? kb : vb);
    gemm_tile_body(A, Wm, bias, out, blockIdx.x * BM, blockIdx.y * BN);
}

__global__ __launch_bounds__(256, 4)
void out_proj_kernel(const float* __restrict__ ao, const float* __restrict__ Wo,
                     const float* __restrict__ bo, float* __restrict__ out)
{
    gemm_tile_body(ao, Wo, bo, out, blockIdx.x * BM, blockIdx.y * BN);
}

// ---------------- local 3D attention ----------------
// block = one (b,s,h) row: 32 w-positions x 8 heads = 256 threads
// thread = (position, head): full per-thread softmax over 27 window slots
__global__ __launch_bounds__(256, 2)
void attn_kernel(const float* __restrict__ qp, const float* __restrict__ kb,
                 const float* __restrict__ vb, float* __restrict__ ao)
{
    int bix = blockIdx.x;            // (b*S + s)*H + h
    int h = bix % H_N;
    int t = bix / H_N;
    int s = t % S_N;
    int b = t / S_N;
    int n = threadIdx.x & 7;
    int w = threadIdx.x >> 3;

    size_t pos = (((size_t)b * S_N + s) * H_N + h) * W_N + w;
    const float* qrow = qp + pos * DIM_N + n * DH_N;
    float qv[DH_N];
#pragma unroll
    for (int i = 0; i < 8; ++i) {
        float4 v = ((const float4*)qrow)[i];
        qv[i * 4 + 0] = v.x; qv[i * 4 + 1] = v.y;
        qv[i * 4 + 2] = v.z; qv[i * 4 + 3] = v.w;
    }

    float dots[27];
#pragma unroll
    for (int dz = 0; dz < 3; ++dz)
#pragma unroll
        for (int dy = 0; dy < 3; ++dy)
#pragma unroll
            for (int dx = 0; dx < 3; ++dx) {
                int idx = (dz * 3 + dy) * 3 + dx;
                int ns = s + dz - 1, nh = h + dy - 1, nw = w + dx - 1;
                bool ok = (unsigned)ns < S_N && (unsigned)nh < H_N &&
                          (unsigned)nw < W_N;
                float d = -1e30f;
                if (ok) {
                    size_t np = (((size_t)b * S_N + ns) * H_N + nh) * W_N + nw;
                    const float* krow = kb + np * DIM_N + n * DH_N;
                    float acc = 0.f;
#pragma unroll
                    for (int i = 0; i < 8; ++i) {
                        float4 v = ((const float4*)krow)[i];
                        acc = fmaf(qv[i * 4 + 0], v.x, acc);
                        acc = fmaf(qv[i * 4 + 1], v.y, acc);
                        acc = fmaf(qv[i * 4 + 2], v.z, acc);
                        acc = fmaf(qv[i * 4 + 3], v.w, acc);
                    }
                    d = acc * SCALE_F;
                }
                dots[idx] = d;
            }

    float m = dots[0];
#pragma unroll
    for (int i = 1; i < 27; ++i) m = fmaxf(m, dots[i]);
    float den = 0.f;
#pragma unroll
    for (int i = 0; i < 27; ++i) {
        float p = __expf(dots[i] - m);   // masked slots: exp(-1e30) == 0
        dots[i] = p;
        den += p;
    }
    float inv = 1.f / den;

    float ov[DH_N];
#pragma unroll
    for (int i = 0; i < DH_N; ++i) ov[i] = 0.f;
#pragma unroll
    for (int dz = 0; dz < 3; ++dz)
#pragma unroll
        for (int dy = 0; dy < 3; ++dy)
#pragma unroll
            for (int dx = 0; dx < 3; ++dx) {
                int idx = (dz * 3 + dy) * 3 + dx;
                int ns = s + dz - 1, nh = h + dy - 1, nw = w + dx - 1;
                bool ok = (unsigned)ns < S_N && (unsigned)nh < H_N &&
                          (unsigned)nw < W_N;
                if (ok) {
                    size_t np = (((size_t)b * S_N + ns) * H_N + nh) * W_N + nw;
                    const float* vrow = vb + np * DIM_N + n * DH_N;
                    float p = dots[idx];
#pragma unroll
                    for (int i = 0; i < 8; ++i) {
                        float4 v = ((const float4*)vrow)[i];
                        ov[i * 4 + 0] = fmaf(p, v.x, ov[i * 4 + 0]);
                        ov[i * 4 + 1] = fmaf(p, v.y, ov[i * 4 + 1]);
                        ov[i * 4 + 2] = fmaf(p, v.z, ov[i * 4 + 2]);
                        ov[i * 4 + 3] = fmaf(p, v.w, ov[i * 4 + 3]);
                    }
                }
            }

    float* orow = ao + pos * DIM_N + n * DH_N;
#pragma unroll
    for (int i = 0; i < 8; ++i) {
        float4 v;
        v.x = ov[i * 4 + 0] * inv;
        v.y = ov[i * 4 + 1] * inv;
        v.z = ov[i * 4 + 2] * inv;
        v.w = ov[i * 4 + 3] * inv;
        ((float4*)orow)[i] = v;
    }
}

// ---------------- launch ----------------
extern "C" void kernel_launch(void* const* d_in, const int* in_sizes, int n_in,
                              void* d_out, int out_size, void* d_ws, size_t ws_size,
                              hipStream_t stream)
{
    const float* x  = (const float*)d_in[0];
    const float* q  = (const float*)d_in[1];
    const float* Wq = (const float*)d_in[2];
    const float* Wk = (const float*)d_in[3];
    const float* Wv = (const float*)d_in[4];
    const float* bv = (const float*)d_in[5];
    const float* Wo = (const float*)d_in[6];
    const float* bo = (const float*)d_in[7];
    float* out = (float*)d_out;

    float* ws = (float*)d_ws;
    float* qp = ws;                                   // 16384*256
    float* kb = qp + (size_t)NPOS * DIM_N;
    float* vb = kb + (size_t)NPOS * DIM_N;
    float* ao = vb + (size_t)NPOS * DIM_N;

    dim3 gp(NPOS / BM, DIM_N / BN, 3);
    proj_kernel<<<gp, 256, 0, stream>>>(x, q, Wq, Wk, Wv, bv, qp, kb, vb);

    attn_kernel<<<B_N * S_N * H_N, 256, 0, stream>>>(qp, kb, vb, ao);

    dim3 go(NPOS / BM, DIM_N / BN, 1);
    out_proj_kernel<<<go, 256, 0, stream>>>(ao, Wo, bo, out);
}

// Round 2
// 81.545 us; speedup vs baseline: 4.8134x; 4.8134x over previous
//
#include <hip/hip_runtime.h>
#include <hip/hip_bf16.h>
#include <math.h>

#define B_N 2
#define S_N 8
#define H_N 32
#define W_N 32
#define DIM_N 256
#define NPOS (B_N * S_N * H_N * W_N)       // 16384
#define NP (NPOS * DIM_N)                  // 4194304 elems per matrix
#define HEADS_N 8
#define DH_N 32
#define SCALE_F 0.1767766952966369f        // 32^-0.5

typedef __attribute__((ext_vector_type(8))) short bf16x8;
typedef __attribute__((ext_vector_type(4))) float f32x4;

__device__ __forceinline__ unsigned short f2b(float f) {
    __hip_bfloat16 h = __float2bfloat16(f);
    return __builtin_bit_cast(unsigned short, h);
}
__device__ __forceinline__ float bl(unsigned u) { return __uint_as_float(u << 16); }
__device__ __forceinline__ float bh(unsigned u) { return __uint_as_float(u & 0xffff0000u); }

// ---------------- fp32 -> bf16 conversion for x / q ----------------
__global__ __launch_bounds__(256)
void cvt_f2b_kernel(const float* __restrict__ x, const float* __restrict__ q,
                    unsigned short* __restrict__ xb, unsigned short* __restrict__ qb)
{
    int i = blockIdx.x * 256 + threadIdx.x;          // per float4
    const float* s = blockIdx.y ? q : x;
    unsigned short* d = blockIdx.y ? qb : xb;
    float4 v = ((const float4*)s)[i];
    ushort4 o;
    o.x = f2b(v.x); o.y = f2b(v.y); o.z = f2b(v.z); o.w = f2b(v.w);
    ((ushort4*)d)[i] = o;
}

// ---------------- weight transpose + convert: Wt[n][k] = bf16(W[k][n]) ----------------
__global__ __launch_bounds__(256)
void wtrans_kernel(const float* __restrict__ Wq, const float* __restrict__ Wk,
                   const float* __restrict__ Wv, const float* __restrict__ Wo,
                   unsigned short* __restrict__ wt)
{
    int mat = blockIdx.y;
    const float* W = (mat == 0) ? Wq : (mat == 1) ? Wk : (mat == 2) ? Wv : Wo;
    unsigned short* Wt = wt + (size_t)mat * 65536;
    int tile = blockIdx.x;                 // 64 tiles of 32x32
    int tk = tile >> 3, tn = tile & 7;
    __shared__ float t[32][33];
    int c = threadIdx.x & 31;
    int r0 = (threadIdx.x >> 5) * 4;
#pragma unroll
    for (int i = 0; i < 4; ++i)
        t[r0 + i][c] = W[(size_t)(tk * 32 + r0 + i) * 256 + tn * 32 + c];
    __syncthreads();
#pragma unroll
    for (int i = 0; i < 4; ++i)
        Wt[(size_t)(tn * 32 + r0 + i) * 256 + tk * 32 + c] = f2b(t[c][r0 + i]);
}

// ---------------- bf16 MFMA GEMM: out[M,256] = A[M,256] @ W, W given as Wt[n][k] ----------------
// 128x128 block tile, 4 waves (2x2), 64x64 per wave, BK=64.
__device__ __forceinline__ void gemm_body(
    const unsigned short* __restrict__ A, const unsigned short* __restrict__ Wt,
    const float* __restrict__ bias, unsigned short* __restrict__ out_b,
    float* __restrict__ out_f, int row0, int col0)
{
    __shared__ unsigned short Al[128][72];   // pad 72: balanced banks, 16B-aligned rows
    __shared__ unsigned short Bl[128][72];

    const int tid = threadIdx.x;
    const int lane = tid & 63;
    const int wid = tid >> 6;
    const int wr = wid >> 1, wc = wid & 1;   // wave 2x2 -> 64x64 tile each
    const int l15 = lane & 15, l4 = lane >> 4;

    f32x4 acc[4][4];
#pragma unroll
    for (int m = 0; m < 4; ++m)
#pragma unroll
        for (int n = 0; n < 4; ++n) acc[m][n] = (f32x4){0.f, 0.f, 0.f, 0.f};

    const int r = tid >> 3, s = tid & 7;     // staging: 8 lanes per row, 16B each

    for (int kt = 0; kt < DIM_N; kt += 64) {
#pragma unroll
        for (int j = 0; j < 4; ++j) {
            int rr = r + j * 32;
            uint4 va = *(const uint4*)&A[(size_t)(row0 + rr) * DIM_N + kt + s * 8];
            *(uint4*)&Al[rr][s * 8] = va;
            uint4 vb = *(const uint4*)&Wt[(size_t)(col0 + rr) * DIM_N + kt + s * 8];
            *(uint4*)&Bl[rr][s * 8] = vb;
        }
        __syncthreads();
#pragma unroll
        for (int ks = 0; ks < 2; ++ks) {
            bf16x8 af[4], bfr[4];
#pragma unroll
            for (int m = 0; m < 4; ++m)
                af[m] = *(const bf16x8*)&Al[wr * 64 + m * 16 + l15][ks * 32 + l4 * 8];
#pragma unroll
            for (int n = 0; n < 4; ++n)
                bfr[n] = *(const bf16x8*)&Bl[wc * 64 + n * 16 + l15][ks * 32 + l4 * 8];
#pragma unroll
            for (int m = 0; m < 4; ++m)
#pragma unroll
                for (int n = 0; n < 4; ++n)
                    acc[m][n] = __builtin_amdgcn_mfma_f32_16x16x32_bf16(
                        af[m], bfr[n], acc[m][n], 0, 0, 0);
        }
        __syncthreads();
    }

    // epilogue: D col = lane&15, row = (lane>>4)*4 + reg   [m89-verified layout]
    const int rowb = row0 + wr * 64 + l4 * 4;
    const int colb = col0 + wc * 64 + l15;
#pragma unroll
    for (int n = 0; n < 4; ++n) {
        int col = colb + n * 16;
        float bb = bias ? bias[col] : 0.f;
#pragma unroll
        for (int m = 0; m < 4; ++m) {
#pragma unroll
            for (int rg = 0; rg < 4; ++rg) {
                int row = rowb + m * 16 + rg;
                float v = acc[m][n][rg] + bb;
                if (out_b) out_b[(size_t)row * DIM_N + col] = f2b(v);
                else       out_f[(size_t)row * DIM_N + col] = v;
            }
        }
    }
}

__global__ __launch_bounds__(256, 2)
void proj_mfma(const unsigned short* __restrict__ xb, const unsigned short* __restrict__ qb,
               const unsigned short* __restrict__ wt, const float* __restrict__ bv,
               unsigned short* __restrict__ qp, unsigned short* __restrict__ kb,
               unsigned short* __restrict__ vb)
{
    int z = blockIdx.z;
    const unsigned short* A = (z == 0) ? qb : xb;
    const unsigned short* W = wt + (size_t)z * 65536;
    unsigned short* out = (z == 0) ? qp : (z == 1) ? kb : vb;
    const float* bias = (z == 2) ? bv : nullptr;
    gemm_body(A, W, bias, out, nullptr, blockIdx.x * 128, blockIdx.y * 128);
}

__global__ __launch_bounds__(256, 2)
void outp_mfma(const unsigned short* __restrict__ ao, const unsigned short* __restrict__ wt,
               const float* __restrict__ bo, float* __restrict__ out)
{
    gemm_body(ao, wt + 3 * 65536, bo, nullptr, out, blockIdx.x * 128, blockIdx.y * 128);
}

// ---------------- local 3D attention (bf16 in/out, fp32 math) ----------------
__global__ __launch_bounds__(256, 2)
void attn_kernel(const unsigned short* __restrict__ qp, const unsigned short* __restrict__ kb,
                 const unsigned short* __restrict__ vb, unsigned short* __restrict__ ao)
{
    int bix = blockIdx.x;                // (b*S + s)*H + h
    int h = bix % H_N;
    int t = bix / H_N;
    int s = t % S_N;
    int b = t / S_N;
    int n = threadIdx.x & 7;
    int w = threadIdx.x >> 3;

    size_t pos = (((size_t)b * S_N + s) * H_N + h) * W_N + w;
    const unsigned short* qrow = qp + pos * DIM_N + n * DH_N;
    float qv[DH_N];
#pragma unroll
    for (int j = 0; j < 4; ++j) {
        uint4 u = ((const uint4*)qrow)[j];
        qv[j * 8 + 0] = bl(u.x); qv[j * 8 + 1] = bh(u.x);
        qv[j * 8 + 2] = bl(u.y); qv[j * 8 + 3] = bh(u.y);
        qv[j * 8 + 4] = bl(u.z); qv[j * 8 + 5] = bh(u.z);
        qv[j * 8 + 6] = bl(u.w); qv[j * 8 + 7] = bh(u.w);
    }

    float dots[27];
#pragma unroll
    for (int dz = 0; dz < 3; ++dz)
#pragma unroll
        for (int dy = 0; dy < 3; ++dy)
#pragma unroll
            for (int dx = 0; dx < 3; ++dx) {
                int idx = (dz * 3 + dy) * 3 + dx;
                int ns = s + dz - 1, nh = h + dy - 1, nw = w + dx - 1;
                bool ok = (unsigned)ns < S_N && (unsigned)nh < H_N &&
                          (unsigned)nw < W_N;
                float d = -1e30f;
                if (ok) {
                    size_t np = (((size_t)b * S_N + ns) * H_N + nh) * W_N + nw;
                    const unsigned short* krow = kb + np * DIM_N + n * DH_N;
                    float acc = 0.f;
#pragma unroll
                    for (int j = 0; j < 4; ++j) {
                        uint4 u = ((const uint4*)krow)[j];
                        acc = fmaf(qv[j * 8 + 0], bl(u.x), acc);
                        acc = fmaf(qv[j * 8 + 1], bh(u.x), acc);
                        acc = fmaf(qv[j * 8 + 2], bl(u.y), acc);
                        acc = fmaf(qv[j * 8 + 3], bh(u.y), acc);
                        acc = fmaf(qv[j * 8 + 4], bl(u.z), acc);
                        acc = fmaf(qv[j * 8 + 5], bh(u.z), acc);
                        acc = fmaf(qv[j * 8 + 6], bl(u.w), acc);
                        acc = fmaf(qv[j * 8 + 7], bh(u.w), acc);
                    }
                    d = acc * SCALE_F;
                }
                dots[idx] = d;
            }

    float m = dots[0];
#pragma unroll
    for (int i = 1; i < 27; ++i) m = fmaxf(m, dots[i]);
    float den = 0.f;
#pragma unroll
    for (int i = 0; i < 27; ++i) {
        float p = __expf(dots[i] - m);       // masked: exp(-1e30) == 0 exactly
        dots[i] = p;
        den += p;
    }
    float inv = 1.f / den;

    float ov[DH_N];
#pragma unroll
    for (int i = 0; i < DH_N; ++i) ov[i] = 0.f;
#pragma unroll
    for (int dz = 0; dz < 3; ++dz)
#pragma unroll
        for (int dy = 0; dy < 3; ++dy)
#pragma unroll
            for (int dx = 0; dx < 3; ++dx) {
                int idx = (dz * 3 + dy) * 3 + dx;
                int ns = s + dz - 1, nh = h + dy - 1, nw = w + dx - 1;
                bool ok = (unsigned)ns < S_N && (unsigned)nh < H_N &&
                          (unsigned)nw < W_N;
                if (ok) {
                    size_t np = (((size_t)b * S_N + ns) * H_N + nh) * W_N + nw;
                    const unsigned short* vrow = vb + np * DIM_N + n * DH_N;
                    float p = dots[idx];
#pragma unroll
                    for (int j = 0; j < 4; ++j) {
                        uint4 u = ((const uint4*)vrow)[j];
                        ov[j * 8 + 0] = fmaf(p, bl(u.x), ov[j * 8 + 0]);
                        ov[j * 8 + 1] = fmaf(p, bh(u.x), ov[j * 8 + 1]);
                        ov[j * 8 + 2] = fmaf(p, bl(u.y), ov[j * 8 + 2]);
                        ov[j * 8 + 3] = fmaf(p, bh(u.y), ov[j * 8 + 3]);
                        ov[j * 8 + 4] = fmaf(p, bl(u.z), ov[j * 8 + 4]);
                        ov[j * 8 + 5] = fmaf(p, bh(u.z), ov[j * 8 + 5]);
                        ov[j * 8 + 6] = fmaf(p, bl(u.w), ov[j * 8 + 6]);
                        ov[j * 8 + 7] = fmaf(p, bh(u.w), ov[j * 8 + 7]);
                    }
                }
            }

    unsigned short* orow = ao + pos * DIM_N + n * DH_N;
#pragma unroll
    for (int j = 0; j < 4; ++j) {
        uint4 o;
        o.x = (unsigned)f2b(ov[j * 8 + 0] * inv) | ((unsigned)f2b(ov[j * 8 + 1] * inv) << 16);
        o.y = (unsigned)f2b(ov[j * 8 + 2] * inv) | ((unsigned)f2b(ov[j * 8 + 3] * inv) << 16);
        o.z = (unsigned)f2b(ov[j * 8 + 4] * inv) | ((unsigned)f2b(ov[j * 8 + 5] * inv) << 16);
        o.w = (unsigned)f2b(ov[j * 8 + 6] * inv) | ((unsigned)f2b(ov[j * 8 + 7] * inv) << 16);
        ((uint4*)orow)[j] = o;
    }
}

// ---------------- launch ----------------
extern "C" void kernel_launch(void* const* d_in, const int* in_sizes, int n_in,
                              void* d_out, int out_size, void* d_ws, size_t ws_size,
                              hipStream_t stream)
{
    const float* xin = (const float*)d_in[0];
    const float* qin = (const float*)d_in[1];
    const float* Wq  = (const float*)d_in[2];
    const float* Wk  = (const float*)d_in[3];
    const float* Wv  = (const float*)d_in[4];
    const float* bv  = (const float*)d_in[5];
    const float* Wo  = (const float*)d_in[6];
    const float* bo  = (const float*)d_in[7];
    float* out = (float*)d_out;

    unsigned short* ws = (unsigned short*)d_ws;
    unsigned short* xb = ws;                    // NP
    unsigned short* qb = xb + (size_t)NP;       // NP
    unsigned short* wt = qb + (size_t)NP;       // 4 * 65536
    unsigned short* qp = wt + (size_t)4 * 65536;
    unsigned short* kb = qp + (size_t)NP;
    unsigned short* vb = kb + (size_t)NP;
    unsigned short* ao = vb + (size_t)NP;

    dim3 gc(NP / 4 / 256, 2);
    cvt_f2b_kernel<<<gc, 256, 0, stream>>>(xin, qin, xb, qb);

    dim3 gw(64, 4);
    wtrans_kernel<<<gw, 256, 0, stream>>>(Wq, Wk, Wv, Wo, wt);

    dim3 gp(NPOS / 128, DIM_N / 128, 3);
    proj_mfma<<<gp, 256, 0, stream>>>(xb, qb, wt, bv, qp, kb, vb);

    attn_kernel<<<B_N * S_N * H_N, 256, 0, stream>>>(qp, kb, vb, ao);

    dim3 go(NPOS / 128, DIM_N / 128, 1);
    outp_mfma<<<go, 256, 0, stream>>>(ao, wt, bo, out);
}

// Round 3
// 73.658 us; speedup vs baseline: 5.3289x; 1.1071x over previous
//
#include <hip/hip_runtime.h>
#include <hip/hip_bf16.h>
#include <math.h>

#define B_N 2
#define S_N 8
#define H_N 32
#define W_N 32
#define DIM_N 256
#define NPOS (B_N * S_N * H_N * W_N)       // 16384
#define NP (NPOS * DIM_N)                  // 4194304
#define SCALE_F 0.1767766952966369f        // 32^-0.5

typedef __attribute__((ext_vector_type(8))) short bf16x8;
typedef __attribute__((ext_vector_type(4))) float f32x4;

__device__ __forceinline__ unsigned short f2b(float f) {
    __hip_bfloat16 h = __float2bfloat16(f);
    return __builtin_bit_cast(unsigned short, h);
}
__device__ __forceinline__ unsigned pk2(float a, float b) {
    return (unsigned)f2b(a) | ((unsigned)f2b(b) << 16);
}
__device__ __forceinline__ float bl(unsigned u) { return __uint_as_float(u << 16); }
__device__ __forceinline__ float bh(unsigned u) { return __uint_as_float(u & 0xffff0000u); }

// ---------------- weight transpose + convert: Wt[n][k] = bf16(W[k][n]) ----------------
__global__ __launch_bounds__(256)
void wtrans_kernel(const float* __restrict__ Wq, const float* __restrict__ Wk,
                   const float* __restrict__ Wv, const float* __restrict__ Wo,
                   unsigned short* __restrict__ wt)
{
    int mat = blockIdx.y;
    const float* W = (mat == 0) ? Wq : (mat == 1) ? Wk : (mat == 2) ? Wv : Wo;
    unsigned short* Wt = wt + (size_t)mat * 65536;
    int tile = blockIdx.x;                 // 64 tiles of 32x32
    int tk = tile >> 3, tn = tile & 7;
    __shared__ float t[32][33];
    int c = threadIdx.x & 31;
    int r0 = (threadIdx.x >> 5) * 4;
#pragma unroll
    for (int i = 0; i < 4; ++i)
        t[r0 + i][c] = W[(size_t)(tk * 32 + r0 + i) * 256 + tn * 32 + c];
    __syncthreads();
#pragma unroll
    for (int i = 0; i < 4; ++i)
        Wt[(size_t)(tn * 32 + r0 + i) * 256 + tk * 32 + c] = f2b(t[c][r0 + i]);
}

// ---------------- bf16 MFMA GEMM ----------------
// 128x128 tile, 4 waves (2x2), BK=64. A either fp32 (convert inline) or bf16.
// Output either head-major bf16 [head][pos][32] or pos-major fp32 [pos][256].
template<bool A_F32, bool OUT_HM>
__device__ __forceinline__ void gemm_body(
    const void* __restrict__ Aptr, const unsigned short* __restrict__ Wt,
    const float* __restrict__ bias, unsigned short* __restrict__ out_hm,
    float* __restrict__ out_f, int row0, int col0)
{
    __shared__ unsigned short Al[128][72];
    __shared__ unsigned short Bl[128][72];

    const int tid = threadIdx.x;
    const int lane = tid & 63;
    const int wid = tid >> 6;
    const int wr = wid >> 1, wc = wid & 1;
    const int l15 = lane & 15, l4 = lane >> 4;

    f32x4 acc[4][4];
#pragma unroll
    for (int m = 0; m < 4; ++m)
#pragma unroll
        for (int n = 0; n < 4; ++n) acc[m][n] = (f32x4){0.f, 0.f, 0.f, 0.f};

    const int r = tid >> 3, s = tid & 7;

    for (int kt = 0; kt < DIM_N; kt += 64) {
#pragma unroll
        for (int j = 0; j < 4; ++j) {
            int rr = r + j * 32;
            if (A_F32) {
                const float* Af = (const float*)Aptr;
                const float* p = &Af[(size_t)(row0 + rr) * DIM_N + kt + s * 8];
                float4 f0 = *(const float4*)p;
                float4 f1 = *(const float4*)(p + 4);
                uint4 va;
                va.x = pk2(f0.x, f0.y); va.y = pk2(f0.z, f0.w);
                va.z = pk2(f1.x, f1.y); va.w = pk2(f1.z, f1.w);
                *(uint4*)&Al[rr][s * 8] = va;
            } else {
                const unsigned short* Ab = (const unsigned short*)Aptr;
                *(uint4*)&Al[rr][s * 8] =
                    *(const uint4*)&Ab[(size_t)(row0 + rr) * DIM_N + kt + s * 8];
            }
            *(uint4*)&Bl[rr][s * 8] =
                *(const uint4*)&Wt[(size_t)(col0 + rr) * DIM_N + kt + s * 8];
        }
        __syncthreads();
#pragma unroll
        for (int ks = 0; ks < 2; ++ks) {
            bf16x8 af[4], bfr[4];
#pragma unroll
            for (int m = 0; m < 4; ++m)
                af[m] = *(const bf16x8*)&Al[wr * 64 + m * 16 + l15][ks * 32 + l4 * 8];
#pragma unroll
            for (int n = 0; n < 4; ++n)
                bfr[n] = *(const bf16x8*)&Bl[wc * 64 + n * 16 + l15][ks * 32 + l4 * 8];
#pragma unroll
            for (int m = 0; m < 4; ++m)
#pragma unroll
                for (int n = 0; n < 4; ++n)
                    acc[m][n] = __builtin_amdgcn_mfma_f32_16x16x32_bf16(
                        af[m], bfr[n], acc[m][n], 0, 0, 0);
        }
        __syncthreads();
    }

    // D layout: col = lane&15, row = (lane>>4)*4 + reg  [m89]
    const int rowb = row0 + wr * 64 + l4 * 4;
    const int colb = col0 + wc * 64 + l15;
#pragma unroll
    for (int n = 0; n < 4; ++n) {
        int col = colb + n * 16;
        float bb = bias ? bias[col] : 0.f;
        int head = col >> 5, dh = col & 31;
#pragma unroll
        for (int m = 0; m < 4; ++m) {
#pragma unroll
            for (int rg = 0; rg < 4; ++rg) {
                int row = rowb + m * 16 + rg;
                float v = acc[m][n][rg] + bb;
                if (OUT_HM)
                    out_hm[((size_t)head * NPOS + row) * 32 + dh] = f2b(v);
                else
                    out_f[(size_t)row * DIM_N + col] = v;
            }
        }
    }
}

__global__ __launch_bounds__(256, 2)
void proj_mfma(const float* __restrict__ x, const float* __restrict__ q,
               const unsigned short* __restrict__ wt, const float* __restrict__ bv,
               unsigned short* __restrict__ qhb, unsigned short* __restrict__ khb,
               unsigned short* __restrict__ vhb)
{
    int z = blockIdx.z;
    const float* A = (z == 0) ? q : x;
    const unsigned short* W = wt + (size_t)z * 65536;
    unsigned short* out = (z == 0) ? qhb : (z == 1) ? khb : vhb;
    const float* bias = (z == 2) ? bv : nullptr;
    gemm_body<true, true>(A, W, bias, out, nullptr, blockIdx.x * 128, blockIdx.y * 128);
}

__global__ __launch_bounds__(256, 2)
void outp_mfma(const unsigned short* __restrict__ ao, const unsigned short* __restrict__ wt,
               const float* __restrict__ bo, float* __restrict__ out)
{
    gemm_body<false, false>(ao, wt + 3 * 65536, bo, nullptr, out,
                            blockIdx.x * 128, blockIdx.y * 128);
}

// ---------------- local 3D attention ----------------
// Head-major q/k/v: buf[head][pos][32]. Block = (b,s,h) row; lane map:
// head = tid>>5, w = tid&31 -> each 32-lane group streams contiguous 2KB rows.
__global__ __launch_bounds__(256, 2)
void attn_kernel(const unsigned short* __restrict__ qh, const unsigned short* __restrict__ kh,
                 const unsigned short* __restrict__ vh, unsigned short* __restrict__ aop)
{
    __shared__ unsigned short aol[32 * 256];    // 16 KB transpose buffer

    int bix = blockIdx.x;
    int h = bix & 31, s = (bix >> 5) & 7, b = bix >> 8;
    int n = threadIdx.x >> 5;       // head
    int w = threadIdx.x & 31;

    size_t rowbase = (((size_t)b * S_N + s) * H_N + h) * W_N;
    size_t pos = rowbase + w;
    const unsigned short* qrow = qh + ((size_t)n * NPOS + pos) * 32;
    float qv[32];
#pragma unroll
    for (int j = 0; j < 4; ++j) {
        uint4 u = ((const uint4*)qrow)[j];
        qv[j * 8 + 0] = bl(u.x); qv[j * 8 + 1] = bh(u.x);
        qv[j * 8 + 2] = bl(u.y); qv[j * 8 + 3] = bh(u.y);
        qv[j * 8 + 4] = bl(u.z); qv[j * 8 + 5] = bh(u.z);
        qv[j * 8 + 6] = bl(u.w); qv[j * 8 + 7] = bh(u.w);
    }

    float dots[27];
#pragma unroll
    for (int dz = 0; dz < 3; ++dz)
#pragma unroll
        for (int dy = 0; dy < 3; ++dy)
#pragma unroll
            for (int dx = 0; dx < 3; ++dx) {
                int idx = (dz * 3 + dy) * 3 + dx;
                int ns = s + dz - 1, nh = h + dy - 1, nw = w + dx - 1;
                bool ok = (unsigned)ns < S_N && (unsigned)nh < H_N &&
                          (unsigned)nw < W_N;
                float d = -1e30f;
                if (ok) {
                    size_t np = (((size_t)b * S_N + ns) * H_N + nh) * W_N + nw;
                    const unsigned short* krow = kh + ((size_t)n * NPOS + np) * 32;
                    float acc = 0.f;
#pragma unroll
                    for (int j = 0; j < 4; ++j) {
                        uint4 u = ((const uint4*)krow)[j];
                        acc = fmaf(qv[j * 8 + 0], bl(u.x), acc);
                        acc = fmaf(qv[j * 8 + 1], bh(u.x), acc);
                        acc = fmaf(qv[j * 8 + 2], bl(u.y), acc);
                        acc = fmaf(qv[j * 8 + 3], bh(u.y), acc);
                        acc = fmaf(qv[j * 8 + 4], bl(u.z), acc);
                        acc = fmaf(qv[j * 8 + 5], bh(u.z), acc);
                        acc = fmaf(qv[j * 8 + 6], bl(u.w), acc);
                        acc = fmaf(qv[j * 8 + 7], bh(u.w), acc);
                    }
                    d = acc * SCALE_F;
                }
                dots[idx] = d;
            }

    float m = dots[0];
#pragma unroll
    for (int i = 1; i < 27; ++i) m = fmaxf(m, dots[i]);
    float den = 0.f;
#pragma unroll
    for (int i = 0; i < 27; ++i) {
        float p = __expf(dots[i] - m);      // masked: exp(-1e30) == 0 exactly
        dots[i] = p;
        den += p;
    }
    float inv = 1.f / den;

    float ov[32];
#pragma unroll
    for (int i = 0; i < 32; ++i) ov[i] = 0.f;
#pragma unroll
    for (int dz = 0; dz < 3; ++dz)
#pragma unroll
        for (int dy = 0; dy < 3; ++dy)
#pragma unroll
            for (int dx = 0; dx < 3; ++dx) {
                int idx = (dz * 3 + dy) * 3 + dx;
                int ns = s + dz - 1, nh = h + dy - 1, nw = w + dx - 1;
                bool ok = (unsigned)ns < S_N && (unsigned)nh < H_N &&
                          (unsigned)nw < W_N;
                if (ok) {
                    size_t np = (((size_t)b * S_N + ns) * H_N + nh) * W_N + nw;
                    const unsigned short* vrow = vh + ((size_t)n * NPOS + np) * 32;
                    float p = dots[idx];
#pragma unroll
                    for (int j = 0; j < 4; ++j) {
                        uint4 u = ((const uint4*)vrow)[j];
                        ov[j * 8 + 0] = fmaf(p, bl(u.x), ov[j * 8 + 0]);
                        ov[j * 8 + 1] = fmaf(p, bh(u.x), ov[j * 8 + 1]);
                        ov[j * 8 + 2] = fmaf(p, bl(u.y), ov[j * 8 + 2]);
                        ov[j * 8 + 3] = fmaf(p, bh(u.y), ov[j * 8 + 3]);
                        ov[j * 8 + 4] = fmaf(p, bl(u.z), ov[j * 8 + 4]);
                        ov[j * 8 + 5] = fmaf(p, bh(u.z), ov[j * 8 + 5]);
                        ov[j * 8 + 6] = fmaf(p, bl(u.w), ov[j * 8 + 6]);
                        ov[j * 8 + 7] = fmaf(p, bh(u.w), ov[j * 8 + 7]);
                    }
                }
            }

    // LDS transpose (XOR swizzle), then coalesced pos-major global write
#pragma unroll
    for (int j = 0; j < 4; ++j) {
        uint4 o;
        o.x = pk2(ov[j * 8 + 0] * inv, ov[j * 8 + 1] * inv);
        o.y = pk2(ov[j * 8 + 2] * inv, ov[j * 8 + 3] * inv);
        o.z = pk2(ov[j * 8 + 4] * inv, ov[j * 8 + 5] * inv);
        o.w = pk2(ov[j * 8 + 6] * inv, ov[j * 8 + 7] * inv);
        int unit = n * 4 + j;                   // 16B unit within the 512B row
        int su = unit ^ (w & 7);
        *(uint4*)&aol[w * 256 + su * 8] = o;
    }
    __syncthreads();
    int wrr = threadIdx.x >> 3, c = threadIdx.x & 7;
    size_t orow = rowbase + wrr;
#pragma unroll
    for (int u = 0; u < 4; ++u) {
        int unit = c * 4 + u;
        int su = unit ^ (wrr & 7);
        uint4 v = *(const uint4*)&aol[wrr * 256 + su * 8];
        ((uint4*)(aop + orow * 256))[unit] = v;
    }
}

// ---------------- launch ----------------
extern "C" void kernel_launch(void* const* d_in, const int* in_sizes, int n_in,
                              void* d_out, int out_size, void* d_ws, size_t ws_size,
                              hipStream_t stream)
{
    const float* xin = (const float*)d_in[0];
    const float* qin = (const float*)d_in[1];
    const float* Wq  = (const float*)d_in[2];
    const float* Wk  = (const float*)d_in[3];
    const float* Wv  = (const float*)d_in[4];
    const float* bv  = (const float*)d_in[5];
    const float* Wo  = (const float*)d_in[6];
    const float* bo  = (const float*)d_in[7];
    float* out = (float*)d_out;

    unsigned short* ws = (unsigned short*)d_ws;
    unsigned short* wt = ws;                        // 4 * 65536
    unsigned short* qh = wt + (size_t)4 * 65536;    // head-major [8][NPOS][32]
    unsigned short* kh = qh + (size_t)NP;
    unsigned short* vh = kh + (size_t)NP;
    unsigned short* ao = vh + (size_t)NP;           // pos-major [NPOS][256]

    dim3 gw(64, 4);
    wtrans_kernel<<<gw, 256, 0, stream>>>(Wq, Wk, Wv, Wo, wt);

    dim3 gp(NPOS / 128, DIM_N / 128, 3);
    proj_mfma<<<gp, 256, 0, stream>>>(xin, qin, wt, bv, qh, kh, vh);

    attn_kernel<<<B_N * S_N * H_N, 256, 0, stream>>>(qh, kh, vh, ao);

    dim3 go(NPOS / 128, DIM_N / 128, 1);
    outp_mfma<<<go, 256, 0, stream>>>(ao, wt, bo, out);
}

// Round 4
// 64.045 us; speedup vs baseline: 6.1287x; 1.1501x over previous
//
#include <hip/hip_runtime.h>
#include <hip/hip_bf16.h>
#include <math.h>

#define B_N 2
#define S_N 8
#define H_N 32
#define W_N 32
#define DIM_N 256
#define NPOS (B_N * S_N * H_N * W_N)       // 16384
#define NP (NPOS * DIM_N)                  // 4194304
#define SCALE_F 0.1767766952966369f        // 32^-0.5

typedef __attribute__((ext_vector_type(8))) short bf16x8;
typedef __attribute__((ext_vector_type(4))) float f32x4;

__device__ __forceinline__ unsigned short f2b(float f) {
    __hip_bfloat16 h = __float2bfloat16(f);
    return __builtin_bit_cast(unsigned short, h);
}
__device__ __forceinline__ unsigned pk2(float a, float b) {
    return (unsigned)f2b(a) | ((unsigned)f2b(b) << 16);
}
__device__ __forceinline__ float bl(unsigned u) { return __uint_as_float(u << 16); }
__device__ __forceinline__ float bh(unsigned u) { return __uint_as_float(u & 0xffff0000u); }

// ---------------- weight transpose + convert: Wt[n][k] = bf16(W[k][n]) ----------------
__global__ __launch_bounds__(256)
void wtrans_kernel(const float* __restrict__ Wq, const float* __restrict__ Wk,
                   const float* __restrict__ Wv, const float* __restrict__ Wo,
                   unsigned short* __restrict__ wt)
{
    int mat = blockIdx.y;
    const float* W = (mat == 0) ? Wq : (mat == 1) ? Wk : (mat == 2) ? Wv : Wo;
    unsigned short* Wt = wt + (size_t)mat * 65536;
    int tile = blockIdx.x;                 // 64 tiles of 32x32
    int tk = tile >> 3, tn = tile & 7;
    __shared__ float t[32][33];
    int c = threadIdx.x & 31;
    int r0 = (threadIdx.x >> 5) * 4;
#pragma unroll
    for (int i = 0; i < 4; ++i)
        t[r0 + i][c] = W[(size_t)(tk * 32 + r0 + i) * 256 + tn * 32 + c];
    __syncthreads();
#pragma unroll
    for (int i = 0; i < 4; ++i)
        Wt[(size_t)(tn * 32 + r0 + i) * 256 + tk * 32 + c] = f2b(t[c][r0 + i]);
}

// ---------------- proj GEMM: 64x256 tile, 8 waves (2m x 4n), BK=64 ----------------
// out head-major bf16 [head][pos][32].  A fp32, converted inline during staging.
__global__ __launch_bounds__(512, 4)
void proj_mfma(const float* __restrict__ x, const float* __restrict__ q,
               const unsigned short* __restrict__ wt, const float* __restrict__ bv,
               unsigned short* __restrict__ qh, unsigned short* __restrict__ kh,
               unsigned short* __restrict__ vh)
{
    __shared__ unsigned short Al[64][72];
    __shared__ unsigned short Bl[256][72];

    const int bx = blockIdx.x;
    const int z = bx >> 8;                  // 0:q 1:k 2:v
    const int row0 = (bx & 255) * 64;
    const float* A = (z == 0) ? q : x;
    const unsigned short* Wtm = wt + (size_t)z * 65536;
    unsigned short* outp = (z == 0) ? qh : (z == 1) ? kh : vh;
    const float* bias = (z == 2) ? bv : nullptr;

    const int tid = threadIdx.x;
    const int lane = tid & 63;
    const int wid = tid >> 6;
    const int wm = wid >> 2, wn = wid & 3;  // wave tile: 32 rows x 64 cols
    const int l15 = lane & 15, l4 = lane >> 4;

    f32x4 acc[2][4];
#pragma unroll
    for (int m = 0; m < 2; ++m)
#pragma unroll
        for (int n = 0; n < 4; ++n) acc[m][n] = (f32x4){0.f, 0.f, 0.f, 0.f};

    const int ar = tid >> 3, as = tid & 7;  // A staging: 8x8-float segments

    for (int kt = 0; kt < DIM_N; kt += 64) {
        {   // A: 64 rows x 64 k fp32 -> bf16
            const float* p = &A[(size_t)(row0 + ar) * DIM_N + kt + as * 8];
            float4 f0 = *(const float4*)p;
            float4 f1 = *(const float4*)(p + 4);
            uint4 va;
            va.x = pk2(f0.x, f0.y); va.y = pk2(f0.z, f0.w);
            va.z = pk2(f1.x, f1.y); va.w = pk2(f1.z, f1.w);
            *(uint4*)&Al[ar][as * 8] = va;
        }
        // B: 256 cols x 64 k bf16 (2048 16B units, 4 per thread)
#pragma unroll
        for (int i = 0; i < 4; ++i) {
            int u = tid + i * 512;
            int rowb = u >> 3, su = u & 7;
            *(uint4*)&Bl[rowb][su * 8] =
                *(const uint4*)&Wtm[(size_t)rowb * DIM_N + kt + su * 8];
        }
        __syncthreads();
#pragma unroll
        for (int ks = 0; ks < 2; ++ks) {
            bf16x8 af[2], bfr[4];
#pragma unroll
            for (int m = 0; m < 2; ++m)
                af[m] = *(const bf16x8*)&Al[wm * 32 + m * 16 + l15][ks * 32 + l4 * 8];
#pragma unroll
            for (int n = 0; n < 4; ++n)
                bfr[n] = *(const bf16x8*)&Bl[wn * 64 + n * 16 + l15][ks * 32 + l4 * 8];
#pragma unroll
            for (int m = 0; m < 2; ++m)
#pragma unroll
                for (int n = 0; n < 4; ++n)
                    acc[m][n] = __builtin_amdgcn_mfma_f32_16x16x32_bf16(
                        af[m], bfr[n], acc[m][n], 0, 0, 0);
        }
        __syncthreads();
    }

    // D layout: col = lane&15, row = (lane>>4)*4 + reg  [m89]
#pragma unroll
    for (int n = 0; n < 4; ++n) {
        int col = wn * 64 + n * 16 + l15;
        float bb = bias ? bias[col] : 0.f;
        int head = col >> 5, dh = col & 31;
#pragma unroll
        for (int m = 0; m < 2; ++m) {
#pragma unroll
            for (int rg = 0; rg < 4; ++rg) {
                int row = row0 + wm * 32 + m * 16 + l4 * 4 + rg;
                outp[((size_t)head * NPOS + row) * 32 + dh] =
                    f2b(acc[m][n][rg] + bb);
            }
        }
    }
}

// ---------------- fused local 3D attention + output projection ----------------
// Block = (b,s,h) row, 256 threads / 4 waves.
// Phase 1: per-thread (head, w) attention -> 32x256 tile in LDS (swizzled).
// Phase 2: tile @ Wo (MFMA, Wo-tile staged per K-step) + bo -> fp32 out.
__global__ __launch_bounds__(256, 3)
void attn_fused(const unsigned short* __restrict__ qh, const unsigned short* __restrict__ kh,
                const unsigned short* __restrict__ vh, const unsigned short* __restrict__ wt3,
                const float* __restrict__ bo, float* __restrict__ out)
{
    __shared__ unsigned short aol[32 * 256];    // 16 KB attention-output tile
    __shared__ unsigned short Bl[256][72];      // 36 KB Wo K-tile

    int bix = blockIdx.x;
    int h = bix & 31, s = (bix >> 5) & 7, b = bix >> 8;
    int n = threadIdx.x >> 5;       // head
    int w = threadIdx.x & 31;

    size_t rowbase = (((size_t)b * S_N + s) * H_N + h) * W_N;
    size_t pos = rowbase + w;
    const unsigned short* qrow = qh + ((size_t)n * NPOS + pos) * 32;
    float qv[32];
#pragma unroll
    for (int j = 0; j < 4; ++j) {
        uint4 u = ((const uint4*)qrow)[j];
        qv[j * 8 + 0] = bl(u.x); qv[j * 8 + 1] = bh(u.x);
        qv[j * 8 + 2] = bl(u.y); qv[j * 8 + 3] = bh(u.y);
        qv[j * 8 + 4] = bl(u.z); qv[j * 8 + 5] = bh(u.z);
        qv[j * 8 + 6] = bl(u.w); qv[j * 8 + 7] = bh(u.w);
    }

    float dots[27];
#pragma unroll
    for (int dz = 0; dz < 3; ++dz)
#pragma unroll
        for (int dy = 0; dy < 3; ++dy)
#pragma unroll
            for (int dx = 0; dx < 3; ++dx) {
                int idx = (dz * 3 + dy) * 3 + dx;
                int ns = s + dz - 1, nh = h + dy - 1, nw = w + dx - 1;
                bool ok = (unsigned)ns < S_N && (unsigned)nh < H_N &&
                          (unsigned)nw < W_N;
                float d = -1e30f;
                if (ok) {
                    size_t np = (((size_t)b * S_N + ns) * H_N + nh) * W_N + nw;
                    const unsigned short* krow = kh + ((size_t)n * NPOS + np) * 32;
                    float acc = 0.f;
#pragma unroll
                    for (int j = 0; j < 4; ++j) {
                        uint4 u = ((const uint4*)krow)[j];
                        acc = fmaf(qv[j * 8 + 0], bl(u.x), acc);
                        acc = fmaf(qv[j * 8 + 1], bh(u.x), acc);
                        acc = fmaf(qv[j * 8 + 2], bl(u.y), acc);
                        acc = fmaf(qv[j * 8 + 3], bh(u.y), acc);
                        acc = fmaf(qv[j * 8 + 4], bl(u.z), acc);
                        acc = fmaf(qv[j * 8 + 5], bh(u.z), acc);
                        acc = fmaf(qv[j * 8 + 6], bl(u.w), acc);
                        acc = fmaf(qv[j * 8 + 7], bh(u.w), acc);
                    }
                    d = acc * SCALE_F;
                }
                dots[idx] = d;
            }

    float m = dots[0];
#pragma unroll
    for (int i = 1; i < 27; ++i) m = fmaxf(m, dots[i]);
    float den = 0.f;
#pragma unroll
    for (int i = 0; i < 27; ++i) {
        float p = __expf(dots[i] - m);      // masked: exp(-1e30) == 0 exactly
        dots[i] = p;
        den += p;
    }
    float inv = 1.f / den;

    float ov[32];
#pragma unroll
    for (int i = 0; i < 32; ++i) ov[i] = 0.f;
#pragma unroll
    for (int dz = 0; dz < 3; ++dz)
#pragma unroll
        for (int dy = 0; dy < 3; ++dy)
#pragma unroll
            for (int dx = 0; dx < 3; ++dx) {
                int idx = (dz * 3 + dy) * 3 + dx;
                int ns = s + dz - 1, nh = h + dy - 1, nw = w + dx - 1;
                bool ok = (unsigned)ns < S_N && (unsigned)nh < H_N &&
                          (unsigned)nw < W_N;
                if (ok) {
                    size_t np = (((size_t)b * S_N + ns) * H_N + nh) * W_N + nw;
                    const unsigned short* vrow = vh + ((size_t)n * NPOS + np) * 32;
                    float p = dots[idx];
#pragma unroll
                    for (int j = 0; j < 4; ++j) {
                        uint4 u = ((const uint4*)vrow)[j];
                        ov[j * 8 + 0] = fmaf(p, bl(u.x), ov[j * 8 + 0]);
                        ov[j * 8 + 1] = fmaf(p, bh(u.x), ov[j * 8 + 1]);
                        ov[j * 8 + 2] = fmaf(p, bl(u.y), ov[j * 8 + 2]);
                        ov[j * 8 + 3] = fmaf(p, bh(u.y), ov[j * 8 + 3]);
                        ov[j * 8 + 4] = fmaf(p, bl(u.z), ov[j * 8 + 4]);
                        ov[j * 8 + 5] = fmaf(p, bh(u.z), ov[j * 8 + 5]);
                        ov[j * 8 + 6] = fmaf(p, bl(u.w), ov[j * 8 + 6]);
                        ov[j * 8 + 7] = fmaf(p, bh(u.w), ov[j * 8 + 7]);
                    }
                }
            }

    // attention tile -> LDS, pos-major rows, 16B units XOR-swizzled by row
#pragma unroll
    for (int j = 0; j < 4; ++j) {
        uint4 o;
        o.x = pk2(ov[j * 8 + 0] * inv, ov[j * 8 + 1] * inv);
        o.y = pk2(ov[j * 8 + 2] * inv, ov[j * 8 + 3] * inv);
        o.z = pk2(ov[j * 8 + 4] * inv, ov[j * 8 + 5] * inv);
        o.w = pk2(ov[j * 8 + 6] * inv, ov[j * 8 + 7] * inv);
        int unit = n * 4 + j;                   // 16B unit within the 512B row
        int su = unit ^ (w & 7);
        *(uint4*)&aol[w * 256 + su * 8] = o;
    }

    // ---- phase 2: out[32,256] = aol @ Wo + bo ----
    const int lane = threadIdx.x & 63;
    const int wv = threadIdx.x >> 6;            // wave -> col block of 64
    const int l15 = lane & 15, l4 = lane >> 4;

    f32x4 acc[2][4];
#pragma unroll
    for (int m2 = 0; m2 < 2; ++m2)
#pragma unroll
        for (int n2 = 0; n2 < 4; ++n2) acc[m2][n2] = (f32x4){0.f, 0.f, 0.f, 0.f};

    for (int kt = 0; kt < 4; ++kt) {
        __syncthreads();                        // aol ready / prev MFMA done with Bl
#pragma unroll
        for (int i = 0; i < 8; ++i) {           // stage Wo K-tile: 2048 16B units
            int u = threadIdx.x + i * 256;
            int rowb = u >> 3, su = u & 7;
            *(uint4*)&Bl[rowb][su * 8] =
                *(const uint4*)&wt3[(size_t)rowb * DIM_N + kt * 64 + su * 8];
        }
        __syncthreads();
#pragma unroll
        for (int ks = 0; ks < 2; ++ks) {
            bf16x8 af[2], bfr[4];
#pragma unroll
            for (int m2 = 0; m2 < 2; ++m2) {
                int r = m2 * 16 + l15;
                int unit = kt * 8 + ks * 4 + l4;
                int su = unit ^ (r & 7);
                af[m2] = *(const bf16x8*)&aol[r * 256 + su * 8];
            }
#pragma unroll
            for (int n2 = 0; n2 < 4; ++n2)
                bfr[n2] = *(const bf16x8*)&Bl[wv * 64 + n2 * 16 + l15][ks * 32 + l4 * 8];
#pragma unroll
            for (int m2 = 0; m2 < 2; ++m2)
#pragma unroll
                for (int n2 = 0; n2 < 4; ++n2)
                    acc[m2][n2] = __builtin_amdgcn_mfma_f32_16x16x32_bf16(
                        af[m2], bfr[n2], acc[m2][n2], 0, 0, 0);
        }
    }

#pragma unroll
    for (int n2 = 0; n2 < 4; ++n2) {
        int col = wv * 64 + n2 * 16 + l15;
        float bb = bo[col];
#pragma unroll
        for (int m2 = 0; m2 < 2; ++m2) {
#pragma unroll
            for (int rg = 0; rg < 4; ++rg) {
                int row = m2 * 16 + l4 * 4 + rg;
                out[(rowbase + row) * DIM_N + col] = acc[m2][n2][rg] + bb;
            }
        }
    }
}

// ---------------- launch ----------------
extern "C" void kernel_launch(void* const* d_in, const int* in_sizes, int n_in,
                              void* d_out, int out_size, void* d_ws, size_t ws_size,
                              hipStream_t stream)
{
    const float* xin = (const float*)d_in[0];
    const float* qin = (const float*)d_in[1];
    const float* Wq  = (const float*)d_in[2];
    const float* Wk  = (const float*)d_in[3];
    const float* Wv  = (const float*)d_in[4];
    const float* bv  = (const float*)d_in[5];
    const float* Wo  = (const float*)d_in[6];
    const float* bo  = (const float*)d_in[7];
    float* out = (float*)d_out;

    unsigned short* ws = (unsigned short*)d_ws;
    unsigned short* wt = ws;                        // 4 * 65536
    unsigned short* qh = wt + (size_t)4 * 65536;    // head-major [8][NPOS][32]
    unsigned short* kh = qh + (size_t)NP;
    unsigned short* vh = kh + (size_t)NP;

    dim3 gw(64, 4);
    wtrans_kernel<<<gw, 256, 0, stream>>>(Wq, Wk, Wv, Wo, wt);

    proj_mfma<<<768, 512, 0, stream>>>(xin, qin, wt, bv, qh, kh, vh);

    attn_fused<<<B_N * S_N * H_N, 256, 0, stream>>>(qh, kh, vh, wt + 3 * 65536, bo, out);
}